// Round 3
// baseline (744.890 us; speedup 1.0000x reference)
//
#include <hip/hip_runtime.h>
#include <cstdint>

// Problem: B=32, N=4096, C=768, H=12, hd=64, L=32, chunk=24
// Identity: out[b,l,c'] = (sum_n attn[b,l,n] x[b,n,:]) . v_w[l*24+c',:] + v_b
// (sum_n attn = 1, value proj is linear) -> value-GEMM collapses to weighted sum.
// Pipeline: KA: E=exp(0.125*q.k) -> ws (bf16, barrier-free, direct-load frags)
//           KW: single sweep: sums_h, rs, W = sum_h rs*E (E held in regs)
//           YA: y[g] = W . x  (x pass 2, MFMA, 16 n-groups)
//           KO: out = (sum_g y) . v_w^T + v_b

typedef short bf16x8 __attribute__((ext_vector_type(8)));
typedef float f32x4 __attribute__((ext_vector_type(4)));

#define MFMA16(a, b, c) __builtin_amdgcn_mfma_f32_16x16x32_bf16((a), (b), (c), 0, 0, 0)

// pack two f32 -> (bf16(a) | bf16(b)<<16) by byte-select (truncation, 1 VALU)
__device__ __forceinline__ uint32_t pk_bf16(float a, float b) {
    return __builtin_amdgcn_perm(__float_as_uint(b), __float_as_uint(a), 0x07060302u);
}
__device__ __forceinline__ unsigned short bf16_trunc(float f) {
    return (unsigned short)(__float_as_uint(f) >> 16);
}
__device__ __forceinline__ float bf16_lo(uint32_t u) { return __uint_as_float(u << 16); }
__device__ __forceinline__ float bf16_hi(uint32_t u) { return __uint_as_float(u & 0xffff0000u); }

__device__ __forceinline__ bf16x8 pack8(float4 a, float4 b) {
    union { uint32_t u[4]; bf16x8 v; } r;
    r.u[0] = pk_bf16(a.x, a.y); r.u[1] = pk_bf16(a.z, a.w);
    r.u[2] = pk_bf16(b.x, b.y); r.u[3] = pk_bf16(b.z, b.w);
    return r.v;
}

// ---------------------------------------------------------------------------
// KA: barrier-free logits. grid 32b x 64 n-tiles = 2048 blocks x 256.
// Wave wv owns n-subtile n0+wv*16..+16. Per h: A-frags from latent (L2-hot),
// B-frags from x rows (16 rows x 128 B dense per (h,k32) pair of loads),
// 4 MFMA (2 l-tiles x 2 k), E = bf16(exp(S*0.125)) scalar-stored.
// MFMA 16x16x32: A[m=lane&15][k=quad*8+j], B[k][n=lane&15],
// D: col=lane&15, row=quad*4+reg.
// ---------------------------------------------------------------------------
__global__ __launch_bounds__(256)
void ka_logits(const float* __restrict__ x, const float* __restrict__ latent,
               unsigned short* __restrict__ E)
{
    const int b  = blockIdx.x >> 6;
    const int n0 = (blockIdx.x & 63) << 6;
    const int wv = threadIdx.x >> 6;
    const int lane = threadIdx.x & 63;
    const int quad = lane >> 4;
    const int lc   = lane & 15;
    const int n = n0 + wv * 16 + lc;

    const float* xr = x + (size_t)(b * 4096 + n) * 768;  // this lane's x row (B: n=lc)
    const float* q0 = latent + lc * 768;                 // A l-tile 0: m=lc
    const float* q1 = latent + (16 + lc) * 768;          // A l-tile 1

    for (int h = 0; h < 12; ++h) {
        const int d0 = h * 64 + quad * 8;   // k32=0 slice; +32 for k32=1

        float4 x0a = *(const float4*)(xr + d0);
        float4 x0b = *(const float4*)(xr + d0 + 4);
        float4 x1a = *(const float4*)(xr + d0 + 32);
        float4 x1b = *(const float4*)(xr + d0 + 36);
        float4 p0a = *(const float4*)(q0 + d0);
        float4 p0b = *(const float4*)(q0 + d0 + 4);
        float4 p1a = *(const float4*)(q0 + d0 + 32);
        float4 p1b = *(const float4*)(q0 + d0 + 36);
        float4 r0a = *(const float4*)(q1 + d0);
        float4 r0b = *(const float4*)(q1 + d0 + 4);
        float4 r1a = *(const float4*)(q1 + d0 + 32);
        float4 r1b = *(const float4*)(q1 + d0 + 36);

        bf16x8 bf0 = pack8(x0a, x0b);   // B, k 0..31
        bf16x8 bf1 = pack8(x1a, x1b);   // B, k 32..63
        bf16x8 a00 = pack8(p0a, p0b);   // A lt0, k 0..31
        bf16x8 a01 = pack8(p1a, p1b);   // A lt0, k 32..63
        bf16x8 a10 = pack8(r0a, r0b);   // A lt1, k 0..31
        bf16x8 a11 = pack8(r1a, r1b);   // A lt1, k 32..63

        f32x4 c0 = {0.f, 0.f, 0.f, 0.f};
        f32x4 c1 = {0.f, 0.f, 0.f, 0.f};
        c0 = MFMA16(a00, bf0, c0);
        c0 = MFMA16(a01, bf1, c0);
        c1 = MFMA16(a10, bf0, c1);
        c1 = MFMA16(a11, bf1, c1);

        unsigned short* Eh = E + (size_t)((b * 12 + h) * 32) * 4096;
        #pragma unroll
        for (int r = 0; r < 4; ++r) {
            // |S*0.125| <~ 0.2: exp without max-subtraction is exact softmax math
            Eh[(quad * 4 + r) * 4096 + n]      = bf16_trunc(__expf(c0[r] * 0.125f));
            Eh[(16 + quad * 4 + r) * 4096 + n] = bf16_trunc(__expf(c1[r] * 0.125f));
        }
    }
}

// ---------------------------------------------------------------------------
// KW: single-sweep softmax-normalize + head-mean. Block = (b,l), 512 thr;
// thread t owns n in [t*8, t*8+8). Holds all 12 heads' E slices in regs
// (12 x uint4), so E is read exactly once. No atomics.
// ---------------------------------------------------------------------------
__global__ __launch_bounds__(512)
void kw_weights(const unsigned short* __restrict__ E, unsigned short* __restrict__ W)
{
    const int b = blockIdx.x >> 5;
    const int l = blockIdx.x & 31;
    const int tid = threadIdx.x;
    const int wv = tid >> 6, lane = tid & 63;

    const unsigned short* Eb = E + (size_t)(b * 384 + l) * 4096;  // + h*131072

    uint4 u[12];
    float s[12];
    #pragma unroll
    for (int h = 0; h < 12; ++h) {
        u[h] = *(const uint4*)(Eb + (size_t)h * 131072 + tid * 8);
        float v = bf16_lo(u[h].x) + bf16_hi(u[h].x) + bf16_lo(u[h].y) + bf16_hi(u[h].y)
                + bf16_lo(u[h].z) + bf16_hi(u[h].z) + bf16_lo(u[h].w) + bf16_hi(u[h].w);
        #pragma unroll
        for (int m = 1; m < 64; m <<= 1) v += __shfl_xor(v, m);
        s[h] = v;
    }

    __shared__ float red[12][8];
    __shared__ float rsl[12];
    if (lane == 0) {
        #pragma unroll
        for (int h = 0; h < 12; ++h) red[h][wv] = s[h];
    }
    __syncthreads();
    if (tid < 12) {
        float t = 0.f;
        #pragma unroll
        for (int w = 0; w < 8; ++w) t += red[tid][w];
        rsl[tid] = 1.0f / (12.0f * t);
    }
    __syncthreads();

    float acc[8];
    #pragma unroll
    for (int i = 0; i < 8; ++i) acc[i] = 0.f;
    #pragma unroll
    for (int h = 0; h < 12; ++h) {
        float r = rsl[h];
        acc[0] += bf16_lo(u[h].x) * r;  acc[1] += bf16_hi(u[h].x) * r;
        acc[2] += bf16_lo(u[h].y) * r;  acc[3] += bf16_hi(u[h].y) * r;
        acc[4] += bf16_lo(u[h].z) * r;  acc[5] += bf16_hi(u[h].z) * r;
        acc[6] += bf16_lo(u[h].w) * r;  acc[7] += bf16_hi(u[h].w) * r;
    }
    uint4 o;
    o.x = pk_bf16(acc[0], acc[1]); o.y = pk_bf16(acc[2], acc[3]);
    o.z = pk_bf16(acc[4], acc[5]); o.w = pk_bf16(acc[6], acc[7]);
    *(uint4*)(W + (size_t)(b * 32 + l) * 4096 + tid * 8) = o;
}

// ---------------------------------------------------------------------------
// YA: y[g][b][l][c] = sum_{n in g*256..+256} W[b][l][n] * x[b][n][c]
// Single-wave blocks, no LDS/barriers. A: 16B loads from W (L2/L3-hot 8MB).
// B: 8 scalar f32 loads (4 dense 64B lines/instr) + 4 v_perm packs.
// grid = 32 b * 12 c-tiles * 16 n-groups = 6144 blocks of 64 (24 waves/CU).
// ---------------------------------------------------------------------------
__global__ __launch_bounds__(64)
void yacc_kernel(const float* __restrict__ x, const unsigned short* __restrict__ W,
                 float* __restrict__ yws)
{
    const int bx  = blockIdx.x;
    const int b   = bx / 192;
    const int rem = bx - b * 192;
    const int ct  = rem % 12;
    const int g   = rem / 12;
    const int lane = threadIdx.x;
    const int quad = lane >> 4;
    const int lc   = lane & 15;
    const int c0   = ct * 64;
    const int nb   = g * 256;

    const float* xb = x + (size_t)b * 4096 * 768;
    const unsigned short* Wb = W + (size_t)b * 32 * 4096;

    f32x4 acc[2][4];
    #pragma unroll
    for (int t = 0; t < 2; ++t)
        #pragma unroll
        for (int s = 0; s < 4; ++s) acc[t][s] = (f32x4){0.f, 0.f, 0.f, 0.f};

    for (int kk = 0; kk < 256; kk += 32) {
        const int n = nb + kk + quad * 8;
        bf16x8 a0 = *(const bf16x8*)&Wb[lc * 4096 + n];
        bf16x8 a1 = *(const bf16x8*)&Wb[(16 + lc) * 4096 + n];
        #pragma unroll
        for (int s = 0; s < 4; ++s) {
            const float* xp = xb + (size_t)n * 768 + c0 + s * 16 + lc;
            float f0 = xp[0], f1 = xp[768], f2 = xp[1536], f3 = xp[2304];
            float f4 = xp[3072], f5 = xp[3840], f6 = xp[4608], f7 = xp[5376];
            union { uint32_t u[4]; bf16x8 v; } bb;
            bb.u[0] = pk_bf16(f0, f1);
            bb.u[1] = pk_bf16(f2, f3);
            bb.u[2] = pk_bf16(f4, f5);
            bb.u[3] = pk_bf16(f6, f7);
            acc[0][s] = MFMA16(a0, bb.v, acc[0][s]);
            acc[1][s] = MFMA16(a1, bb.v, acc[1][s]);
        }
    }

    float* yp = yws + (size_t)((g * 32 + b) * 32) * 768;
    #pragma unroll
    for (int t = 0; t < 2; ++t)
        #pragma unroll
        for (int s = 0; s < 4; ++s)
            #pragma unroll
            for (int r = 0; r < 4; ++r)
                yp[(t * 16 + quad * 4 + r) * 768 + c0 + s * 16 + lc] = acc[t][s][r];
}

// ---------------------------------------------------------------------------
// KO: out[b, l*24+i] = sum_c (sum_g y[g,b,l,c]) * v_w[l*24+i, c] + v_b
// ---------------------------------------------------------------------------
__global__ __launch_bounds__(256)
void out_kernel(const float* __restrict__ yws, const float* __restrict__ vw,
                const float* __restrict__ vb, float* __restrict__ out)
{
    const int b = blockIdx.x >> 5;
    const int l = blockIdx.x & 31;
    const int tid = threadIdx.x;
    __shared__ float y_lds[768];
    for (int c = tid; c < 768; c += 256) {
        float v = 0.f;
        #pragma unroll
        for (int g = 0; g < 16; ++g)
            v += yws[(size_t)((g * 32 + b) * 32 + l) * 768 + c];
        y_lds[c] = v;
    }
    __syncthreads();
    const int wv = tid >> 6, lane = tid & 63;
    for (int i = wv; i < 24; i += 4) {
        const int row = l * 24 + i;
        const float* wr = vw + row * 768;
        float p = 0.f;
        #pragma unroll
        for (int j = 0; j < 12; ++j)
            p += y_lds[j * 64 + lane] * wr[j * 64 + lane];
        #pragma unroll
        for (int m = 1; m < 64; m <<= 1) p += __shfl_xor(p, m);
        if (lane == 0) out[b * 768 + row] = p + vb[row];
    }
}

// ---------------------------------------------------------------------------
extern "C" void kernel_launch(void* const* d_in, const int* in_sizes, int n_in,
                              void* d_out, int out_size, void* d_ws, size_t ws_size,
                              hipStream_t stream)
{
    const float* x      = (const float*)d_in[0];  // [32,4096,768]
    const float* latent = (const float*)d_in[1];  // [1,32,768]
    const float* vw     = (const float*)d_in[2];  // [768,768]
    const float* vb     = (const float*)d_in[3];  // [768]
    float* out = (float*)d_out;                   // [32,768]

    // ws layout (~152 MB; ws_size ~1.6 GB):
    //   [0, 100663296)            E   bf16[32][12][32][4096]
    //   [100663296, 109051904)    W   bf16[32][32][4096]
    //   [109051904, 159383552)    y   f32[16][32][32][768]
    char* ws = (char*)d_ws;
    unsigned short* E   = (unsigned short*)ws;
    unsigned short* W   = (unsigned short*)(ws + 100663296);
    float*          yws = (float*)(ws + 109051904);

    ka_logits<<<dim3(2048), dim3(256), 0, stream>>>(x, latent, E);
    kw_weights<<<dim3(1024), dim3(512), 0, stream>>>(E, W);
    yacc_kernel<<<dim3(6144), dim3(64), 0, stream>>>(x, W, yws);
    out_kernel<<<dim3(1024), dim3(256), 0, stream>>>(yws, vw, vb, out);
}